// Round 4
// baseline (276.084 us; speedup 1.0000x reference)
//
#include <hip/hip_runtime.h>
#include <hip/hip_bf16.h>

#define H_DIM 1024
#define E_NUM 8
#define F_DIM 2048
#define N_TOK 2048   // B*S
typedef unsigned int uint;
typedef short bf16x8 __attribute__((ext_vector_type(8)));
typedef float f32x4 __attribute__((ext_vector_type(4)));

// ws layout (total ~25.3 MB)
#define WS_CNT   0
#define WS_LIST  256                       // int[8*2048]
#define WS_W     (WS_LIST + 8*N_TOK*4)     // float[4096]
#define WS_G     131072                    // bf16 [4096][2048] = 16 MB (k-PERMUTED rows)
#define WS_Y     (WS_G + 4096*2048*2)      // bf16 [4096][1024] = 8 MB
#define WS_XB    WS_Y                      // bf16 x [2048][1024] (k-PERMUTED), dead before y written

// Row k-permutation: storage position of element k is
//   pi(k) = ((k>>5)*4 + ((k>>2)&3))*8 + ((k>>4)&1)*4 + (k&3)
// block-local to every 64-k step; each 16B chunk is one MFMA A-fragment k-set.

static __device__ __forceinline__ uint f2bf(float f) {
    uint u = __builtin_bit_cast(uint, f);
    return (u + 0x7FFFu + ((u >> 16) & 1u)) >> 16;   // RNE
}
static __device__ __forceinline__ float bflo(uint u) { return __builtin_bit_cast(float, u << 16); }
static __device__ __forceinline__ float bfhi(uint u) { return __builtin_bit_cast(float, u & 0xFFFF0000u); }
static __device__ __forceinline__ uint cvtpk(float a, float b) {
    uint r;
    asm("v_cvt_pk_bf16_f32 %0, %1, %2" : "=v"(r) : "v"(a), "v"(b));  // a->low16, b->high16
    return r;
}
static __device__ __forceinline__ void gload_lds16(const void* g, void* l) {
    __builtin_amdgcn_global_load_lds(
        (const __attribute__((address_space(1))) unsigned int*)g,
        (__attribute__((address_space(3))) unsigned int*)l,
        16, 0, 0);
}

// ---------------- x -> bf16, k-permuted ----------------
__global__ __launch_bounds__(256) void cvt_x_kernel(const float* __restrict__ x,
                                                    unsigned short* __restrict__ xb)
{
    int c = blockIdx.x * 256 + threadIdx.x;
    int row = c >> 7, b = c & 127;
    int t = b >> 3, s = b & 7;
    int klo = t*64 + (s >> 2)*32 + (s & 3)*4;
    const float* xr = x + (size_t)row * H_DIM;
    float4 lo = *(const float4*)(xr + klo);
    float4 hi = *(const float4*)(xr + klo + 16);
    uint4 o;
    o.x = cvtpk(lo.x, lo.y); o.y = cvtpk(lo.z, lo.w);
    o.z = cvtpk(hi.x, hi.y); o.w = cvtpk(hi.z, hi.w);
    *(uint4*)(xb + (size_t)row * H_DIM + b*8) = o;
}

// ---------------- router ----------------
__global__ __launch_bounds__(256) void router_kernel(
    const float* __restrict__ x, const float* __restrict__ rw,
    int* __restrict__ cnt, int* __restrict__ list, float* __restrict__ w_entry)
{
    int wave = threadIdx.x >> 6, lane = threadIdx.x & 63;
    int n = blockIdx.x * 4 + wave;
    const float* xr = x + (size_t)n * H_DIM;
    float acc[8] = {0,0,0,0,0,0,0,0};
    #pragma unroll
    for (int i = 0; i < H_DIM/64; ++i) {
        int h = i*64 + lane;
        float xv = xr[h];
        const float4* rr = (const float4*)(rw + (size_t)h*8);
        float4 r0 = rr[0], r1 = rr[1];
        acc[0] += xv*r0.x; acc[1] += xv*r0.y; acc[2] += xv*r0.z; acc[3] += xv*r0.w;
        acc[4] += xv*r1.x; acc[5] += xv*r1.y; acc[6] += xv*r1.z; acc[7] += xv*r1.w;
    }
    #pragma unroll
    for (int e = 0; e < 8; ++e) {
        float v = acc[e];
        #pragma unroll
        for (int off = 32; off; off >>= 1) v += __shfl_xor(v, off);
        acc[e] = v;
    }
    int e0 = 0;
    #pragma unroll
    for (int e = 1; e < 8; ++e) if (acc[e] > acc[e0]) e0 = e;
    int e1 = -1;
    #pragma unroll
    for (int e = 0; e < 8; ++e) if (e != e0 && (e1 < 0 || acc[e] > acc[e1])) e1 = e;
    float w0 = 1.0f / (1.0f + __expf(acc[e1] - acc[e0]));
    float w1 = 1.0f - w0;
    if (lane == 0) {
        int p0 = atomicAdd(&cnt[e0], 1);
        list[e0*N_TOK + p0] = n*2;
        w_entry[n*2] = w0;
        int p1 = atomicAdd(&cnt[e1], 1);
        list[e1*N_TOK + p1] = n*2 + 1;
        w_entry[n*2+1] = w1;
    }
}

// ---------------- fused expert GEMM (2-phase double-buffered pipeline) ----------------
template<int IS_G1>
__global__ __launch_bounds__(256, 2) void moe_gemm_kernel(
    const unsigned short* __restrict__ Asrc, const float* __restrict__ W,
    const int* __restrict__ cnt, const int* __restrict__ list,
    const float* __restrict__ w_entry, unsigned short* __restrict__ dst)
{
    constexpr int KTOT  = IS_G1 ? H_DIM : F_DIM;
    constexpr int BLD   = IS_G1 ? 2*F_DIM : H_DIM;
    constexpr int DLD   = IS_G1 ? F_DIM : H_DIM;
    constexpr int ALD   = IS_G1 ? H_DIM : F_DIM;
    constexpr int NNT   = IS_G1 ? 32 : 16;
    constexpr int NMT   = 16;
    constexpr int BSROW = IS_G1 ? 512 : 256;
    constexpr int NJ    = IS_G1 ? 4 : 2;
    constexpr int NBS   = IS_G1 ? 4 : 2;
    constexpr int NT    = KTOT / 64;
    constexpr int ABYTES = 128*64*2;                 // 16 KB per A buffer
    constexpr int BBYTES = 32*BSROW;                 // 16/8 KB per B buffer

    __shared__ __align__(16) unsigned short As[2][128*64];
    __shared__ __align__(16) uint Bs[2][BBYTES/4];
    __shared__ int   s_entry[128];
    __shared__ float s_wrow[128];

    constexpr int nb = NMT * NNT * E_NUM;
    constexpr int chunk = nb >> 3;
    int bid = blockIdx.x;
    int f  = (bid & 7) * chunk + (bid >> 3);
    int mt = f % NMT;
    int nt = (f / NMT) % NNT;
    int e  = f / (NMT * NNT);

    const int c = cnt[e];
    if (mt * 128 >= c) return;
    const int tid = threadIdx.x;

    if (tid < 128) {
        int r = mt*128 + tid;
        int rr = r < c ? r : c - 1;
        int ent = list[e*N_TOK + rr];
        s_entry[tid] = ent;
        if constexpr (!IS_G1) s_wrow[tid] = w_entry[ent];
    }
    __syncthreads();

    const int lane = tid & 63, wid = tid >> 6;
    const int wr = wid >> 1, wc = wid & 1;
    const int l15 = lane & 15, lg = lane >> 4;

    // A staging sources (pre-swizzled for linear glds dest == bank-swizzled layout)
    const unsigned short* a_src[4];
    #pragma unroll
    for (int i = 0; i < 4; ++i) {
        int sl  = wid*4096 + i*1024 + lane*16;
        int row = sl >> 7;
        int kb  = ((sl >> 4) & 7) ^ (row & 7);
        int ent = s_entry[row];
        int arow = IS_G1 ? (ent >> 1) : ent;
        a_src[i] = Asrc + (size_t)arow * ALD + kb*8;
    }

    // B staging src/dst
    const float* Wb = W + (size_t)e * (size_t)(IS_G1 ? H_DIM*2*F_DIM : F_DIM*H_DIM);
    const float* b_src[NBS]; int b_dst[NBS];
    #pragma unroll
    for (int s = 0; s < NBS; ++s) {
        int q = tid + s*256;
        int kp, c4, gc;
        if constexpr (IS_G1) {
            kp = q >> 5; c4 = q & 31;
            gc = (c4 < 16) ? (nt*64 + 4*c4) : (F_DIM + nt*64 + 4*(c4-16));
        } else {
            kp = q >> 4; c4 = q & 15;
            gc = nt*64 + 4*c4;
        }
        b_src[s] = Wb + (size_t)(2*kp) * BLD + gc;
        b_dst[s] = (kp*BSROW + c4*16) ^ ((kp & 4) << 4);
    }

    // fragment addresses (byte-identical to round-3-verified layout)
    int a_addr[4][2];
    #pragma unroll
    for (int m = 0; m < 4; ++m)
        #pragma unroll
        for (int kk = 0; kk < 2; ++kk) {
            int row = wr*64 + m*16 + l15;
            a_addr[m][kk] = row*128 + ((kk*64 + lg*16) ^ ((row & 7) << 4));
        }
    int b_base[NJ][2];
    const int xorv = ((2*lg) & 4) << 4;
    #pragma unroll
    for (int j = 0; j < NJ; ++j) {
        int cb = IS_G1 ? ((j < 2) ? (wc*2 + j) : (4 + wc*2 + (j-2))) : (wc*2 + j);
        int co = ((cb*16 + l15) * 4) ^ xorv;
        #pragma unroll
        for (int kk = 0; kk < 2; ++kk)
            b_base[j][kk] = (kk*16 + 2*lg)*BSROW + co;
    }

    f32x4 acc[4][NJ];
    #pragma unroll
    for (int m = 0; m < 4; ++m)
        #pragma unroll
        for (int j = 0; j < NJ; ++j) acc[m][j] = (f32x4){0.f,0.f,0.f,0.f};

    auto compute_step = [&](const char* ab, const char* bb0) {
        #pragma unroll
        for (int kk = 0; kk < 2; ++kk) {
            bf16x8 af[4];
            #pragma unroll
            for (int m = 0; m < 4; ++m)
                af[m] = *(const bf16x8*)(ab + a_addr[m][kk]);
            bf16x8 bfr[NJ];
            #pragma unroll
            for (int j = 0; j < NJ; ++j) {
                const char* bb = bb0 + b_base[j][kk];
                union { uint u[4]; bf16x8 v; } bu;
                bu.u[0] = *(const uint*)(bb);
                bu.u[1] = *(const uint*)(bb + BSROW);
                bu.u[2] = *(const uint*)(bb + 8*BSROW);
                bu.u[3] = *(const uint*)(bb + 9*BSROW);
                bfr[j] = bu.v;
            }
            #pragma unroll
            for (int m = 0; m < 4; ++m)
                #pragma unroll
                for (int j = 0; j < NJ; ++j)
                    acc[m][j] = __builtin_amdgcn_mfma_f32_16x16x32_bf16(af[m], bfr[j], acc[m][j], 0, 0, 0);
        }
    };

    // ---- prologue: stage t=0 into buffer 0 ----
    #pragma unroll
    for (int i = 0; i < 4; ++i)
        gload_lds16(a_src[i], (char*)As[0] + wid*4096 + i*1024);
    {
        float4 r0[NBS], r1[NBS];
        #pragma unroll
        for (int s = 0; s < NBS; ++s) {
            r0[s] = *(const float4*)(b_src[s]);
            r1[s] = *(const float4*)(b_src[s] + BLD);
        }
        #pragma unroll
        for (int s = 0; s < NBS; ++s) {
            uint4 w4;
            w4.x = cvtpk(r0[s].x, r1[s].x); w4.y = cvtpk(r0[s].y, r1[s].y);
            w4.z = cvtpk(r0[s].z, r1[s].z); w4.w = cvtpk(r0[s].w, r1[s].w);
            *(uint4*)((char*)Bs[0] + b_dst[s]) = w4;
        }
    }
    __syncthreads();

    // ---- main loop: prefetch t+1 (issue early), compute t, write B(t+1) late ----
    for (int t = 0; t < NT - 1; ++t) {
        const int cb_ = t & 1, nb_ = cb_ ^ 1;
        // issue next A directly to LDS (stays in flight across compute)
        #pragma unroll
        for (int i = 0; i < 4; ++i)
            gload_lds16(a_src[i] + (t+1)*64, (char*)As[nb_] + wid*4096 + i*1024);
        // issue next B to regs
        float4 r0[NBS], r1[NBS];
        #pragma unroll
        for (int s = 0; s < NBS; ++s) {
            const float* b0 = b_src[s] + (size_t)(t+1) * 64 * BLD;
            r0[s] = *(const float4*)b0;
            r1[s] = *(const float4*)(b0 + BLD);
        }
        // compute current (hides the latency of the loads above)
        compute_step((const char*)As[cb_], (const char*)Bs[cb_]);
        // convert + write next B (compiler inserts the vmcnt wait here)
        #pragma unroll
        for (int s = 0; s < NBS; ++s) {
            uint4 w4;
            w4.x = cvtpk(r0[s].x, r1[s].x); w4.y = cvtpk(r0[s].y, r1[s].y);
            w4.z = cvtpk(r0[s].z, r1[s].z); w4.w = cvtpk(r0[s].w, r1[s].w);
            *(uint4*)((char*)Bs[nb_] + b_dst[s]) = w4;
        }
        __syncthreads();
    }
    compute_step((const char*)As[(NT-1) & 1], (const char*)Bs[(NT-1) & 1]);

    // ---- epilogue ----
    if constexpr (IS_G1) {
        // write g in the k-PERMUTED layout GEMM2's A path expects
        const int pbase = (nt*2 + wc)*32 + (l15 >> 2)*8 + (l15 & 3);
        #pragma unroll
        for (int m = 0; m < 4; ++m)
            #pragma unroll
            for (int jj = 0; jj < 2; ++jj) {
                f32x4 ga = acc[m][jj], gv = acc[m][jj+2];
                #pragma unroll
                for (int i = 0; i < 4; ++i) {
                    int rl = wr*64 + m*16 + lg*4 + i;
                    if (mt*128 + rl < c) {
                        int ent = s_entry[rl];
                        float a = ga[i];
                        float g = (a / (1.f + __expf(-a))) * gv[i];
                        dst[(size_t)ent * DLD + pbase + jj*4] = (unsigned short)f2bf(g);
                    }
                }
            }
    } else {
        #pragma unroll
        for (int m = 0; m < 4; ++m)
            #pragma unroll
            for (int j = 0; j < NJ; ++j) {
                #pragma unroll
                for (int i = 0; i < 4; ++i) {
                    int rl = wr*64 + m*16 + lg*4 + i;
                    if (mt*128 + rl < c) {
                        int ent = s_entry[rl];
                        float v = s_wrow[rl] * acc[m][j][i];
                        int col = nt*64 + wc*32 + j*16 + l15;
                        dst[(size_t)ent * DLD + col] = (unsigned short)f2bf(v);
                    }
                }
            }
    }
}

// ---------------- combine ----------------
__global__ __launch_bounds__(256) void combine_kernel(
    const unsigned short* __restrict__ y, float* __restrict__ out)
{
    int gid = blockIdx.x * 256 + threadIdx.x;
    size_t base = (size_t)gid * 8;
    int n = (int)(base >> 10), h = (int)(base & 1023);
    const uint4 a = *(const uint4*)(y + (size_t)(2*n)   * 1024 + h);
    const uint4 b = *(const uint4*)(y + (size_t)(2*n+1) * 1024 + h);
    float4 o0, o1;
    o0.x = bflo(a.x)+bflo(b.x); o0.y = bfhi(a.x)+bfhi(b.x);
    o0.z = bflo(a.y)+bflo(b.y); o0.w = bfhi(a.y)+bfhi(b.y);
    o1.x = bflo(a.z)+bflo(b.z); o1.y = bfhi(a.z)+bfhi(b.z);
    o1.z = bflo(a.w)+bflo(b.w); o1.w = bfhi(a.w)+bfhi(b.w);
    *(float4*)(out + base)     = o0;
    *(float4*)(out + base + 4) = o1;
}

extern "C" void kernel_launch(void* const* d_in, const int* in_sizes, int n_in,
                              void* d_out, int out_size, void* d_ws, size_t ws_size,
                              hipStream_t stream) {
    const float* x  = (const float*)d_in[0];
    const float* rw = (const float*)d_in[1];
    const float* W1 = (const float*)d_in[2];
    const float* W2 = (const float*)d_in[3];
    float* out = (float*)d_out;
    char* ws = (char*)d_ws;
    int*   cnt     = (int*)(ws + WS_CNT);
    int*   list    = (int*)(ws + WS_LIST);
    float* w_entry = (float*)(ws + WS_W);
    unsigned short* g  = (unsigned short*)(ws + WS_G);
    unsigned short* y  = (unsigned short*)(ws + WS_Y);
    unsigned short* xb = (unsigned short*)(ws + WS_XB);

    hipMemsetAsync(cnt, 0, E_NUM * sizeof(int), stream);
    cvt_x_kernel<<<N_TOK*H_DIM/2048, 256, 0, stream>>>(x, xb);
    router_kernel<<<N_TOK/4, 256, 0, stream>>>(x, rw, cnt, list, w_entry);
    moe_gemm_kernel<1><<<16*32*E_NUM, 256, 0, stream>>>(xb, W1, cnt, list, w_entry, g);
    moe_gemm_kernel<0><<<16*16*E_NUM, 256, 0, stream>>>(g,  W2, cnt, list, w_entry, y);
    combine_kernel<<<(out_size/8 + 255)/256, 256, 0, stream>>>(y, out);
}

// Round 5
// 225.114 us; speedup vs baseline: 1.2264x; 1.2264x over previous
//
#include <hip/hip_runtime.h>
#include <hip/hip_bf16.h>

#define H_DIM 1024
#define E_NUM 8
#define F_DIM 2048
#define N_TOK 2048   // B*S
typedef unsigned int uint;
typedef short bf16x8 __attribute__((ext_vector_type(8)));
typedef float f32x4 __attribute__((ext_vector_type(4)));

// ws layout (total ~25.3 MB)
#define WS_CNT   0
#define WS_LIST  256                       // int[8*2048]
#define WS_W     (WS_LIST + 8*N_TOK*4)     // float[4096]
#define WS_G     131072                    // bf16 [4096][2048] = 16 MB (k-PERMUTED rows)
#define WS_Y     (WS_G + 4096*2048*2)      // bf16 [4096][1024] = 8 MB
#define WS_XB    WS_Y                      // bf16 x [2048][1024] (k-PERMUTED), dead before y written

// Row k-permutation: storage position of element k is
//   pi(k) = ((k>>5)*4 + ((k>>2)&3))*8 + ((k>>4)&1)*4 + (k&3)
// block-local to every 64-k step; each 16B chunk is one MFMA A-fragment k-set.

static __device__ __forceinline__ uint f2bf(float f) {
    uint u = __builtin_bit_cast(uint, f);
    return (u + 0x7FFFu + ((u >> 16) & 1u)) >> 16;   // RNE
}
static __device__ __forceinline__ float bflo(uint u) { return __builtin_bit_cast(float, u << 16); }
static __device__ __forceinline__ float bfhi(uint u) { return __builtin_bit_cast(float, u & 0xFFFF0000u); }
static __device__ __forceinline__ uint cvtpk(float a, float b) {
    uint r;
    asm("v_cvt_pk_bf16_f32 %0, %1, %2" : "=v"(r) : "v"(a), "v"(b));  // a->low16, b->high16
    return r;
}
static __device__ __forceinline__ void gload_lds16(const void* g, void* l) {
    __builtin_amdgcn_global_load_lds(
        (const __attribute__((address_space(1))) unsigned int*)g,
        (__attribute__((address_space(3))) unsigned int*)l,
        16, 0, 0);
}

// ---------------- x -> bf16, k-permuted ----------------
__global__ __launch_bounds__(256) void cvt_x_kernel(const float* __restrict__ x,
                                                    unsigned short* __restrict__ xb)
{
    int c = blockIdx.x * 256 + threadIdx.x;
    int row = c >> 7, b = c & 127;
    int t = b >> 3, s = b & 7;
    int klo = t*64 + (s >> 2)*32 + (s & 3)*4;
    const float* xr = x + (size_t)row * H_DIM;
    float4 lo = *(const float4*)(xr + klo);
    float4 hi = *(const float4*)(xr + klo + 16);
    uint4 o;
    o.x = cvtpk(lo.x, lo.y); o.y = cvtpk(lo.z, lo.w);
    o.z = cvtpk(hi.x, hi.y); o.w = cvtpk(hi.z, hi.w);
    *(uint4*)(xb + (size_t)row * H_DIM + b*8) = o;
}

// ---------------- router ----------------
__global__ __launch_bounds__(256) void router_kernel(
    const float* __restrict__ x, const float* __restrict__ rw,
    int* __restrict__ cnt, int* __restrict__ list, float* __restrict__ w_entry)
{
    int wave = threadIdx.x >> 6, lane = threadIdx.x & 63;
    int n = blockIdx.x * 4 + wave;
    const float* xr = x + (size_t)n * H_DIM;
    float acc[8] = {0,0,0,0,0,0,0,0};
    #pragma unroll
    for (int i = 0; i < H_DIM/64; ++i) {
        int h = i*64 + lane;
        float xv = xr[h];
        const float4* rr = (const float4*)(rw + (size_t)h*8);
        float4 r0 = rr[0], r1 = rr[1];
        acc[0] += xv*r0.x; acc[1] += xv*r0.y; acc[2] += xv*r0.z; acc[3] += xv*r0.w;
        acc[4] += xv*r1.x; acc[5] += xv*r1.y; acc[6] += xv*r1.z; acc[7] += xv*r1.w;
    }
    #pragma unroll
    for (int e = 0; e < 8; ++e) {
        float v = acc[e];
        #pragma unroll
        for (int off = 32; off; off >>= 1) v += __shfl_xor(v, off);
        acc[e] = v;
    }
    int e0 = 0;
    #pragma unroll
    for (int e = 1; e < 8; ++e) if (acc[e] > acc[e0]) e0 = e;
    int e1 = -1;
    #pragma unroll
    for (int e = 0; e < 8; ++e) if (e != e0 && (e1 < 0 || acc[e] > acc[e1])) e1 = e;
    float w0 = 1.0f / (1.0f + __expf(acc[e1] - acc[e0]));
    float w1 = 1.0f - w0;
    if (lane == 0) {
        int p0 = atomicAdd(&cnt[e0], 1);
        list[e0*N_TOK + p0] = n*2;
        w_entry[n*2] = w0;
        int p1 = atomicAdd(&cnt[e1], 1);
        list[e1*N_TOK + p1] = n*2 + 1;
        w_entry[n*2+1] = w1;
    }
}

// ---------------- fused expert GEMM ----------------
// Schedule: A double-buffered (glds, issued pre-compute), B single-buffered
// (regs across compute, ds_write post-barrier). 128x128 tiles both GEMMs.
template<int IS_G1>
__global__ __launch_bounds__(256, 3) void moe_gemm_kernel(
    const unsigned short* __restrict__ Asrc, const float* __restrict__ W,
    const int* __restrict__ cnt, const int* __restrict__ list,
    const float* __restrict__ w_entry, unsigned short* __restrict__ dst)
{
    constexpr int KTOT  = IS_G1 ? H_DIM : F_DIM;
    constexpr int BLD   = IS_G1 ? 2*F_DIM : H_DIM;   // W row stride (fp32)
    constexpr int DLD   = IS_G1 ? F_DIM : H_DIM;     // dst row stride
    constexpr int ALD   = IS_G1 ? H_DIM : F_DIM;     // A src row stride (shorts)
    constexpr int NNT   = IS_G1 ? 32 : 8;            // 128-wide tiles both
    constexpr int NMT   = 16;
    constexpr int BSROW = 512;
    constexpr int NT    = KTOT / 64;

    __shared__ __align__(16) unsigned short As[2][128*64];  // 2 x 16 KB
    __shared__ __align__(16) uint Bs[32*128];               // 16 KB, single
    __shared__ int   s_entry[128];
    __shared__ float s_wrow[128];

    constexpr int nb = NMT * NNT * E_NUM;
    constexpr int chunk = nb >> 3;
    int bid = blockIdx.x;
    int f  = (bid & 7) * chunk + (bid >> 3);
    int mt = f % NMT;
    int nt = (f / NMT) % NNT;
    int e  = f / (NMT * NNT);

    const int c = cnt[e];
    if (mt * 128 >= c) return;
    const int tid = threadIdx.x;

    if (tid < 128) {
        int r = mt*128 + tid;
        int rr = r < c ? r : c - 1;
        int ent = list[e*N_TOK + rr];
        s_entry[tid] = ent;
        if constexpr (!IS_G1) s_wrow[tid] = w_entry[ent];
    }
    __syncthreads();

    const int lane = tid & 63, wid = tid >> 6;
    const int wr = wid >> 1, wc = wid & 1;
    const int l15 = lane & 15, lg = lane >> 4;

    // A staging sources (pre-swizzled for linear glds dest == bank-swizzled layout)
    const unsigned short* a_src[4];
    #pragma unroll
    for (int i = 0; i < 4; ++i) {
        int sl  = wid*4096 + i*1024 + lane*16;
        int row = sl >> 7;
        int kb  = ((sl >> 4) & 7) ^ (row & 7);
        int ent = s_entry[row];
        int arow = IS_G1 ? (ent >> 1) : ent;
        a_src[i] = Asrc + (size_t)arow * ALD + kb*8;
    }

    // B staging src/dst (4 uint4 per thread per K-step)
    const float* Wb = W + (size_t)e * (size_t)(IS_G1 ? H_DIM*2*F_DIM : F_DIM*H_DIM);
    const float* b_src[4]; int b_dst[4];
    #pragma unroll
    for (int s = 0; s < 4; ++s) {
        int q = tid + s*256;
        int kp = q >> 5, c4 = q & 31;
        int gc;
        if constexpr (IS_G1) gc = (c4 < 16) ? (nt*64 + 4*c4) : (F_DIM + nt*64 + 4*(c4-16));
        else                 gc = nt*128 + 4*c4;
        b_src[s] = Wb + (size_t)(2*kp) * BLD + gc;
        b_dst[s] = (kp*BSROW + c4*16) ^ ((kp & 4) << 4);
    }

    // fragment addresses (byte-identical to round-3-verified layout)
    int a_addr[4][2];
    #pragma unroll
    for (int m = 0; m < 4; ++m)
        #pragma unroll
        for (int kk = 0; kk < 2; ++kk) {
            int row = wr*64 + m*16 + l15;
            a_addr[m][kk] = row*128 + ((kk*64 + lg*16) ^ ((row & 7) << 4));
        }
    int b_base[4][2];
    const int xorv = ((2*lg) & 4) << 4;
    #pragma unroll
    for (int j = 0; j < 4; ++j) {
        int cb = IS_G1 ? ((j < 2) ? (wc*2 + j) : (4 + wc*2 + (j-2))) : (wc*4 + j);
        int co = ((cb*16 + l15) * 4) ^ xorv;
        #pragma unroll
        for (int kk = 0; kk < 2; ++kk)
            b_base[j][kk] = (kk*16 + 2*lg)*BSROW + co;
    }

    f32x4 acc[4][4];
    #pragma unroll
    for (int m = 0; m < 4; ++m)
        #pragma unroll
        for (int j = 0; j < 4; ++j) acc[m][j] = (f32x4){0.f,0.f,0.f,0.f};

    auto compute_step = [&](const char* ab) {
        #pragma unroll
        for (int kk = 0; kk < 2; ++kk) {
            bf16x8 af[4];
            #pragma unroll
            for (int m = 0; m < 4; ++m)
                af[m] = *(const bf16x8*)(ab + a_addr[m][kk]);
            bf16x8 bfr[4];
            #pragma unroll
            for (int j = 0; j < 4; ++j) {
                const char* bb = (const char*)Bs + b_base[j][kk];
                union { uint u[4]; bf16x8 v; } bu;
                bu.u[0] = *(const uint*)(bb);
                bu.u[1] = *(const uint*)(bb + BSROW);
                bu.u[2] = *(const uint*)(bb + 8*BSROW);
                bu.u[3] = *(const uint*)(bb + 9*BSROW);
                bfr[j] = bu.v;
            }
            #pragma unroll
            for (int m = 0; m < 4; ++m)
                #pragma unroll
                for (int j = 0; j < 4; ++j)
                    acc[m][j] = __builtin_amdgcn_mfma_f32_16x16x32_bf16(af[m], bfr[j], acc[m][j], 0, 0, 0);
        }
    };

    // ---- prologue: stage t=0 ----
    #pragma unroll
    for (int i = 0; i < 4; ++i)
        gload_lds16(a_src[i], (char*)As[0] + wid*4096 + i*1024);
    {
        float4 r0[4], r1[4];
        #pragma unroll
        for (int s = 0; s < 4; ++s) {
            r0[s] = *(const float4*)(b_src[s]);
            r1[s] = *(const float4*)(b_src[s] + BLD);
        }
        #pragma unroll
        for (int s = 0; s < 4; ++s) {
            uint4 w4;
            w4.x = cvtpk(r0[s].x, r1[s].x); w4.y = cvtpk(r0[s].y, r1[s].y);
            w4.z = cvtpk(r0[s].z, r1[s].z); w4.w = cvtpk(r0[s].w, r1[s].w);
            *(uint4*)((char*)Bs + b_dst[s]) = w4;
        }
    }
    __syncthreads();

    // ---- main loop ----
    for (int t = 0; t < NT; ++t) {
        float4 r0[4], r1[4];
        const bool more = (t + 1 < NT);
        if (more) {
            // issue next-A direct to other LDS buffer (in flight across compute)
            #pragma unroll
            for (int i = 0; i < 4; ++i)
                gload_lds16(a_src[i] + (t+1)*64, (char*)As[(t+1) & 1] + wid*4096 + i*1024);
            // issue next-B to regs (in flight across compute)
            #pragma unroll
            for (int s = 0; s < 4; ++s) {
                const float* b0 = b_src[s] + (size_t)(t+1) * 64 * BLD;
                r0[s] = *(const float4*)b0;
                r1[s] = *(const float4*)(b0 + BLD);
            }
        }
        compute_step((const char*)As[t & 1]);
        __syncthreads();            // all waves done reading Bs (and drains prefetches, now covered)
        if (more) {
            #pragma unroll
            for (int s = 0; s < 4; ++s) {
                uint4 w4;
                w4.x = cvtpk(r0[s].x, r1[s].x); w4.y = cvtpk(r0[s].y, r1[s].y);
                w4.z = cvtpk(r0[s].z, r1[s].z); w4.w = cvtpk(r0[s].w, r1[s].w);
                *(uint4*)((char*)Bs + b_dst[s]) = w4;
            }
            __syncthreads();        // Bs(t+1) visible before next compute
        }
    }

    // ---- epilogue ----
    if constexpr (IS_G1) {
        // write g in the k-PERMUTED layout GEMM2's A path expects
        const int pbase = (nt*2 + wc)*32 + (l15 >> 2)*8 + (l15 & 3);
        #pragma unroll
        for (int m = 0; m < 4; ++m)
            #pragma unroll
            for (int jj = 0; jj < 2; ++jj) {
                f32x4 ga = acc[m][jj], gv = acc[m][jj+2];
                #pragma unroll
                for (int i = 0; i < 4; ++i) {
                    int rl = wr*64 + m*16 + lg*4 + i;
                    if (mt*128 + rl < c) {
                        int ent = s_entry[rl];
                        float a = ga[i];
                        float g = (a / (1.f + __expf(-a))) * gv[i];
                        dst[(size_t)ent * DLD + pbase + jj*4] = (unsigned short)f2bf(g);
                    }
                }
            }
    } else {
        #pragma unroll
        for (int m = 0; m < 4; ++m)
            #pragma unroll
            for (int j = 0; j < 4; ++j) {
                #pragma unroll
                for (int i = 0; i < 4; ++i) {
                    int rl = wr*64 + m*16 + lg*4 + i;
                    if (mt*128 + rl < c) {
                        int ent = s_entry[rl];
                        float v = s_wrow[rl] * acc[m][j][i];
                        int col = nt*128 + wc*64 + j*16 + l15;
                        dst[(size_t)ent * DLD + col] = (unsigned short)f2bf(v);
                    }
                }
            }
    }
}

// ---------------- combine ----------------
__global__ __launch_bounds__(256) void combine_kernel(
    const unsigned short* __restrict__ y, float* __restrict__ out)
{
    int gid = blockIdx.x * 256 + threadIdx.x;
    size_t base = (size_t)gid * 8;
    int n = (int)(base >> 10), h = (int)(base & 1023);
    const uint4 a = *(const uint4*)(y + (size_t)(2*n)   * 1024 + h);
    const uint4 b = *(const uint4*)(y + (size_t)(2*n+1) * 1024 + h);
    float4 o0, o1;
    o0.x = bflo(a.x)+bflo(b.x); o0.y = bfhi(a.x)+bfhi(b.x);
    o0.z = bflo(a.y)+bflo(b.y); o0.w = bfhi(a.y)+bfhi(b.y);
    o1.x = bflo(a.z)+bflo(b.z); o1.y = bfhi(a.z)+bfhi(b.z);
    o1.z = bflo(a.w)+bflo(b.w); o1.w = bfhi(a.w)+bfhi(b.w);
    *(float4*)(out + base)     = o0;
    *(float4*)(out + base + 4) = o1;
}

extern "C" void kernel_launch(void* const* d_in, const int* in_sizes, int n_in,
                              void* d_out, int out_size, void* d_ws, size_t ws_size,
                              hipStream_t stream) {
    const float* x  = (const float*)d_in[0];
    const float* rw = (const float*)d_in[1];
    const float* W1 = (const float*)d_in[2];
    const float* W2 = (const float*)d_in[3];
    float* out = (float*)d_out;
    char* ws = (char*)d_ws;
    int*   cnt     = (int*)(ws + WS_CNT);
    int*   list    = (int*)(ws + WS_LIST);
    float* w_entry = (float*)(ws + WS_W);
    unsigned short* g  = (unsigned short*)(ws + WS_G);
    unsigned short* y  = (unsigned short*)(ws + WS_Y);
    unsigned short* xb = (unsigned short*)(ws + WS_XB);

    hipMemsetAsync(cnt, 0, E_NUM * sizeof(int), stream);
    cvt_x_kernel<<<N_TOK*H_DIM/2048, 256, 0, stream>>>(x, xb);
    router_kernel<<<N_TOK/4, 256, 0, stream>>>(x, rw, cnt, list, w_entry);
    moe_gemm_kernel<1><<<16*32*E_NUM, 256, 0, stream>>>(xb, W1, cnt, list, w_entry, g);
    moe_gemm_kernel<0><<<16*8*E_NUM, 256, 0, stream>>>(g,  W2, cnt, list, w_entry, y);
    combine_kernel<<<(out_size/8 + 255)/256, 256, 0, stream>>>(y, out);
}

// Round 6
// 207.507 us; speedup vs baseline: 1.3305x; 1.0849x over previous
//
#include <hip/hip_runtime.h>
#include <hip/hip_bf16.h>

#define H_DIM 1024
#define E_NUM 8
#define F_DIM 2048
#define N_TOK 2048   // B*S
typedef unsigned int uint;
typedef short bf16x8 __attribute__((ext_vector_type(8)));
typedef float f32x4 __attribute__((ext_vector_type(4)));

// ws layout (total ~25.3 MB)
#define WS_CNT   0
#define WS_LIST  256                       // int[8*2048]
#define WS_W     (WS_LIST + 8*N_TOK*4)     // float[4096]
#define WS_G     131072                    // bf16 [4096][2048] = 16 MB (k-PERMUTED rows)
#define WS_Y     (WS_G + 4096*2048*2)      // bf16 [4096][1024] = 8 MB
#define WS_XB    WS_Y                      // bf16 x [2048][1024] (k-PERMUTED), dead before y written

// Row k-permutation: storage position of element k is
//   pi(k) = ((k>>5)*4 + ((k>>2)&3))*8 + ((k>>4)&1)*4 + (k&3)
// block-local to every 64-k step; each 16B chunk is one MFMA A-fragment k-set.

static __device__ __forceinline__ uint f2bf(float f) {
    uint u = __builtin_bit_cast(uint, f);
    return (u + 0x7FFFu + ((u >> 16) & 1u)) >> 16;   // RNE
}
static __device__ __forceinline__ float bflo(uint u) { return __builtin_bit_cast(float, u << 16); }
static __device__ __forceinline__ float bfhi(uint u) { return __builtin_bit_cast(float, u & 0xFFFF0000u); }
static __device__ __forceinline__ uint cvtpk(float a, float b) {
    uint r;
    asm("v_cvt_pk_bf16_f32 %0, %1, %2" : "=v"(r) : "v"(a), "v"(b));  // a->low16, b->high16
    return r;
}
static __device__ __forceinline__ void gload_lds16(const void* g, void* l) {
    __builtin_amdgcn_global_load_lds(
        (const __attribute__((address_space(1))) unsigned int*)g,
        (__attribute__((address_space(3))) unsigned int*)l,
        16, 0, 0);
}

// ---------------- x -> bf16, k-permuted ----------------
__global__ __launch_bounds__(256) void cvt_x_kernel(const float* __restrict__ x,
                                                    unsigned short* __restrict__ xb)
{
    int c = blockIdx.x * 256 + threadIdx.x;
    int row = c >> 7, b = c & 127;
    int t = b >> 3, s = b & 7;
    int klo = t*64 + (s >> 2)*32 + (s & 3)*4;
    const float* xr = x + (size_t)row * H_DIM;
    float4 lo = *(const float4*)(xr + klo);
    float4 hi = *(const float4*)(xr + klo + 16);
    uint4 o;
    o.x = cvtpk(lo.x, lo.y); o.y = cvtpk(lo.z, lo.w);
    o.z = cvtpk(hi.x, hi.y); o.w = cvtpk(hi.z, hi.w);
    *(uint4*)(xb + (size_t)row * H_DIM + b*8) = o;
}

// ---------------- router ----------------
__global__ __launch_bounds__(256) void router_kernel(
    const float* __restrict__ x, const float* __restrict__ rw,
    int* __restrict__ cnt, int* __restrict__ list, float* __restrict__ w_entry)
{
    int wave = threadIdx.x >> 6, lane = threadIdx.x & 63;
    int n = blockIdx.x * 4 + wave;
    const float* xr = x + (size_t)n * H_DIM;
    float acc[8] = {0,0,0,0,0,0,0,0};
    #pragma unroll
    for (int i = 0; i < H_DIM/64; ++i) {
        int h = i*64 + lane;
        float xv = xr[h];
        const float4* rr = (const float4*)(rw + (size_t)h*8);
        float4 r0 = rr[0], r1 = rr[1];
        acc[0] += xv*r0.x; acc[1] += xv*r0.y; acc[2] += xv*r0.z; acc[3] += xv*r0.w;
        acc[4] += xv*r1.x; acc[5] += xv*r1.y; acc[6] += xv*r1.z; acc[7] += xv*r1.w;
    }
    #pragma unroll
    for (int e = 0; e < 8; ++e) {
        float v = acc[e];
        #pragma unroll
        for (int off = 32; off; off >>= 1) v += __shfl_xor(v, off);
        acc[e] = v;
    }
    int e0 = 0;
    #pragma unroll
    for (int e = 1; e < 8; ++e) if (acc[e] > acc[e0]) e0 = e;
    int e1 = -1;
    #pragma unroll
    for (int e = 0; e < 8; ++e) if (e != e0 && (e1 < 0 || acc[e] > acc[e1])) e1 = e;
    float w0 = 1.0f / (1.0f + __expf(acc[e1] - acc[e0]));
    float w1 = 1.0f - w0;
    if (lane == 0) {
        int p0 = atomicAdd(&cnt[e0], 1);
        list[e0*N_TOK + p0] = n*2;
        w_entry[n*2] = w0;
        int p1 = atomicAdd(&cnt[e1], 1);
        list[e1*N_TOK + p1] = n*2 + 1;
        w_entry[n*2+1] = w1;
    }
}

// ---------------- fused expert GEMM ----------------
// 64-row M-tiles for occupancy. G1: 64x128 (4 waves col-split, 1 gate + 1 value
// 16-col block per wave). G2: 64x64 (2x2 waves). BK=64. A glds-double-buffered,
// B single-buffered reg-staged. All byte mappings identical to verified r3/r5.
template<int IS_G1>
__global__ __launch_bounds__(256, 4) void moe_gemm_kernel(
    const unsigned short* __restrict__ Asrc, const float* __restrict__ W,
    const int* __restrict__ cnt, const int* __restrict__ list,
    const float* __restrict__ w_entry, unsigned short* __restrict__ dst)
{
    constexpr int KTOT  = IS_G1 ? H_DIM : F_DIM;
    constexpr int BLD   = IS_G1 ? 2*F_DIM : H_DIM;   // W row stride (fp32)
    constexpr int DLD   = IS_G1 ? F_DIM : H_DIM;     // dst row stride
    constexpr int ALD   = IS_G1 ? H_DIM : F_DIM;     // A src row stride (shorts)
    constexpr int NMT   = 32;                        // 64-row tiles, c<=2048
    constexpr int NNT   = IS_G1 ? 32 : 16;
    constexpr int BSROW = IS_G1 ? 512 : 256;         // Bs k-pair row bytes
    constexpr int NBS   = IS_G1 ? 4 : 2;             // B uint4s per thread per step
    constexpr int NM    = IS_G1 ? 4 : 2;             // A m-frags per wave
    constexpr int NT    = KTOT / 64;

    __shared__ __align__(16) unsigned short As[2][64*64];   // 2 x 8 KB
    __shared__ __align__(16) uint Bs[32*BSROW/4];           // 16/8 KB single
    __shared__ int   s_entry[64];
    __shared__ float s_wrow[64];

    constexpr int nb = NMT * NNT * E_NUM;
    constexpr int chunk = nb >> 3;                   // = one expert's blocks
    int bid = blockIdx.x;
    int f  = (bid & 7) * chunk + (bid >> 3);
    int mt = f % NMT;
    int nt = (f / NMT) % NNT;
    int e  = f / (NMT * NNT);

    const int c = cnt[e];
    if (mt * 64 >= c) return;
    const int tid = threadIdx.x;

    if (tid < 64) {
        int r = mt*64 + tid;
        int rr = r < c ? r : c - 1;
        int ent = list[e*N_TOK + rr];
        s_entry[tid] = ent;
        if constexpr (!IS_G1) s_wrow[tid] = w_entry[ent];
    }
    __syncthreads();

    const int lane = tid & 63, wid = tid >> 6;
    const int l15 = lane & 15, lg = lane >> 4;
    const int wr = IS_G1 ? 0 : (wid >> 1);           // G2 row-half
    const int wc = wid & 1;                          // G2 col-half
    const int rowbase = IS_G1 ? 0 : wr*32;

    // A staging sources (pre-swizzled so linear glds dest == bank-swizzled layout)
    const unsigned short* a_src[2];
    #pragma unroll
    for (int i = 0; i < 2; ++i) {
        int sl  = wid*2048 + i*1024 + lane*16;       // linear LDS byte slot
        int row = sl >> 7;                           // 128B per row (BK=64)
        int kb  = ((sl >> 4) & 7) ^ (row & 7);       // inverse bank swizzle
        int ent = s_entry[row];
        int arow = IS_G1 ? (ent >> 1) : ent;
        a_src[i] = Asrc + (size_t)arow * ALD + kb*8;
    }

    // B staging src/dst
    const float* Wb = W + (size_t)e * (size_t)(IS_G1 ? H_DIM*2*F_DIM : F_DIM*H_DIM);
    const float* b_src[NBS]; int b_dst[NBS];
    #pragma unroll
    for (int s = 0; s < NBS; ++s) {
        int q = tid + s*256;
        int kp, c4, gc;
        if constexpr (IS_G1) {
            kp = q >> 5; c4 = q & 31;
            gc = (c4 < 16) ? (nt*64 + 4*c4) : (F_DIM + nt*64 + 4*(c4-16));
        } else {
            kp = q >> 4; c4 = q & 15;
            gc = nt*64 + 4*c4;
        }
        b_src[s] = Wb + (size_t)(2*kp) * BLD + gc;
        b_dst[s] = (kp*BSROW + c4*16) ^ ((kp & 4) << 4);
    }

    // fragment addresses (verified formulas, rows now < 64)
    int a_addr[NM][2];
    #pragma unroll
    for (int m = 0; m < NM; ++m)
        #pragma unroll
        for (int kk = 0; kk < 2; ++kk) {
            int row = rowbase + m*16 + l15;
            a_addr[m][kk] = row*128 + ((kk*64 + lg*16) ^ ((row & 7) << 4));
        }
    int b_base[2][2];
    const int xorv = ((2*lg) & 4) << 4;
    #pragma unroll
    for (int j = 0; j < 2; ++j) {
        int cb = IS_G1 ? (j ? (4 + wid) : wid) : (wc*2 + j);
        int co = ((cb*16 + l15) * 4) ^ xorv;
        #pragma unroll
        for (int kk = 0; kk < 2; ++kk)
            b_base[j][kk] = (kk*16 + 2*lg)*BSROW + co;
    }

    f32x4 acc[NM][2];
    #pragma unroll
    for (int m = 0; m < NM; ++m)
        #pragma unroll
        for (int j = 0; j < 2; ++j) acc[m][j] = (f32x4){0.f,0.f,0.f,0.f};

    auto compute_step = [&](const char* ab) {
        #pragma unroll
        for (int kk = 0; kk < 2; ++kk) {
            bf16x8 af[NM];
            #pragma unroll
            for (int m = 0; m < NM; ++m)
                af[m] = *(const bf16x8*)(ab + a_addr[m][kk]);
            bf16x8 bfr[2];
            #pragma unroll
            for (int j = 0; j < 2; ++j) {
                const char* bb = (const char*)Bs + b_base[j][kk];
                union { uint u[4]; bf16x8 v; } bu;
                bu.u[0] = *(const uint*)(bb);
                bu.u[1] = *(const uint*)(bb + BSROW);
                bu.u[2] = *(const uint*)(bb + 8*BSROW);
                bu.u[3] = *(const uint*)(bb + 9*BSROW);
                bfr[j] = bu.v;
            }
            #pragma unroll
            for (int m = 0; m < NM; ++m)
                #pragma unroll
                for (int j = 0; j < 2; ++j)
                    acc[m][j] = __builtin_amdgcn_mfma_f32_16x16x32_bf16(af[m], bfr[j], acc[m][j], 0, 0, 0);
        }
    };

    // ---- prologue: stage t=0 ----
    #pragma unroll
    for (int i = 0; i < 2; ++i)
        gload_lds16(a_src[i], (char*)As[0] + wid*2048 + i*1024);
    {
        float4 r0[NBS], r1[NBS];
        #pragma unroll
        for (int s = 0; s < NBS; ++s) {
            r0[s] = *(const float4*)(b_src[s]);
            r1[s] = *(const float4*)(b_src[s] + BLD);
        }
        #pragma unroll
        for (int s = 0; s < NBS; ++s) {
            uint4 w4;
            w4.x = cvtpk(r0[s].x, r1[s].x); w4.y = cvtpk(r0[s].y, r1[s].y);
            w4.z = cvtpk(r0[s].z, r1[s].z); w4.w = cvtpk(r0[s].w, r1[s].w);
            *(uint4*)((char*)Bs + b_dst[s]) = w4;
        }
    }
    __syncthreads();

    // ---- main loop ----
    for (int t = 0; t < NT; ++t) {
        float4 r0[NBS], r1[NBS];
        const bool more = (t + 1 < NT);
        if (more) {
            #pragma unroll
            for (int i = 0; i < 2; ++i)
                gload_lds16(a_src[i] + (t+1)*64, (char*)As[(t+1) & 1] + wid*2048 + i*1024);
            #pragma unroll
            for (int s = 0; s < NBS; ++s) {
                const float* b0 = b_src[s] + (size_t)(t+1) * 64 * BLD;
                r0[s] = *(const float4*)b0;
                r1[s] = *(const float4*)(b0 + BLD);
            }
        }
        compute_step((const char*)As[t & 1]);
        __syncthreads();
        if (more) {
            #pragma unroll
            for (int s = 0; s < NBS; ++s) {
                uint4 w4;
                w4.x = cvtpk(r0[s].x, r1[s].x); w4.y = cvtpk(r0[s].y, r1[s].y);
                w4.z = cvtpk(r0[s].z, r1[s].z); w4.w = cvtpk(r0[s].w, r1[s].w);
                *(uint4*)((char*)Bs + b_dst[s]) = w4;
            }
            __syncthreads();
        }
    }

    // ---- epilogue ----
    if constexpr (IS_G1) {
        // g F-col for this wave: f0 = nt*64 + wid*16 + l15 (gate), +F (value)
        // permuted pos = nt*64 + ((wid>>1)*4 + (l15>>2))*8 + (wid&1)*4 + (l15&3)
        const int pbase = nt*64 + ((wid >> 1)*4 + (l15 >> 2))*8 + (wid & 1)*4 + (l15 & 3);
        #pragma unroll
        for (int m = 0; m < NM; ++m) {
            f32x4 ga = acc[m][0], gv = acc[m][1];
            #pragma unroll
            for (int i = 0; i < 4; ++i) {
                int rl = m*16 + lg*4 + i;
                if (mt*64 + rl < c) {
                    int ent = s_entry[rl];
                    float a = ga[i];
                    float g = (a / (1.f + __expf(-a))) * gv[i];
                    dst[(size_t)ent * DLD + pbase] = (unsigned short)f2bf(g);
                }
            }
        }
    } else {
        #pragma unroll
        for (int m = 0; m < NM; ++m)
            #pragma unroll
            for (int j = 0; j < 2; ++j) {
                #pragma unroll
                for (int i = 0; i < 4; ++i) {
                    int rl = rowbase + m*16 + lg*4 + i;
                    if (mt*64 + rl < c) {
                        int ent = s_entry[rl];
                        float v = s_wrow[rl] * acc[m][j][i];
                        int col = nt*64 + wc*32 + j*16 + l15;
                        dst[(size_t)ent * DLD + col] = (unsigned short)f2bf(v);
                    }
                }
            }
    }
}

// ---------------- combine ----------------
__global__ __launch_bounds__(256) void combine_kernel(
    const unsigned short* __restrict__ y, float* __restrict__ out)
{
    int gid = blockIdx.x * 256 + threadIdx.x;
    size_t base = (size_t)gid * 8;
    int n = (int)(base >> 10), h = (int)(base & 1023);
    const uint4 a = *(const uint4*)(y + (size_t)(2*n)   * 1024 + h);
    const uint4 b = *(const uint4*)(y + (size_t)(2*n+1) * 1024 + h);
    float4 o0, o1;
    o0.x = bflo(a.x)+bflo(b.x); o0.y = bfhi(a.x)+bfhi(b.x);
    o0.z = bflo(a.y)+bflo(b.y); o0.w = bfhi(a.y)+bfhi(b.y);
    o1.x = bflo(a.z)+bflo(b.z); o1.y = bfhi(a.z)+bfhi(b.z);
    o1.z = bflo(a.w)+bflo(b.w); o1.w = bfhi(a.w)+bfhi(b.w);
    *(float4*)(out + base)     = o0;
    *(float4*)(out + base + 4) = o1;
}

extern "C" void kernel_launch(void* const* d_in, const int* in_sizes, int n_in,
                              void* d_out, int out_size, void* d_ws, size_t ws_size,
                              hipStream_t stream) {
    const float* x  = (const float*)d_in[0];
    const float* rw = (const float*)d_in[1];
    const float* W1 = (const float*)d_in[2];
    const float* W2 = (const float*)d_in[3];
    float* out = (float*)d_out;
    char* ws = (char*)d_ws;
    int*   cnt     = (int*)(ws + WS_CNT);
    int*   list    = (int*)(ws + WS_LIST);
    float* w_entry = (float*)(ws + WS_W);
    unsigned short* g  = (unsigned short*)(ws + WS_G);
    unsigned short* y  = (unsigned short*)(ws + WS_Y);
    unsigned short* xb = (unsigned short*)(ws + WS_XB);

    hipMemsetAsync(cnt, 0, E_NUM * sizeof(int), stream);
    cvt_x_kernel<<<N_TOK*H_DIM/2048, 256, 0, stream>>>(x, xb);
    router_kernel<<<N_TOK/4, 256, 0, stream>>>(x, rw, cnt, list, w_entry);
    moe_gemm_kernel<1><<<32*32*E_NUM, 256, 0, stream>>>(xb, W1, cnt, list, w_entry, g);
    moe_gemm_kernel<0><<<32*16*E_NUM, 256, 0, stream>>>(g,  W2, cnt, list, w_entry, y);
    combine_kernel<<<(out_size/8 + 255)/256, 256, 0, stream>>>(y, out);
}